// Round 7
// baseline (309.108 us; speedup 1.0000x reference)
//
#include <hip/hip_runtime.h>

typedef __bf16 bf16;
typedef __bf16 bf16x4 __attribute__((ext_vector_type(4)));
typedef __bf16 bf16x8 __attribute__((ext_vector_type(8)));
typedef float  f32x4  __attribute__((ext_vector_type(4)));
typedef float  f32x16 __attribute__((ext_vector_type(16)));

#define GLDS16(gsrc, ldst)                                                    \
  __builtin_amdgcn_global_load_lds(                                          \
      (const __attribute__((address_space(1))) void*)(gsrc),                 \
      (__attribute__((address_space(3))) void*)(ldst), 16, 0, 0)

#define MFMA16(a, b, c) __builtin_amdgcn_mfma_f32_16x16x32_bf16((a), (b), (c), 0, 0, 0)
#define MFMA32(a, b, c) __builtin_amdgcn_mfma_f32_32x32x16_bf16((a), (b), (c), 0, 0, 0)
// exchange a's hi-32-lane half with b's lo-32-lane half (gfx950)
#define PLSWAP(a, b) asm volatile("v_permlane32_swap_b32 %0, %1" : "+v"(a), "+v"(b))

__device__ inline unsigned pk2(float a, float b) {
  union { bf16 h[2]; unsigned u; } t;
  t.h[0] = (bf16)a; t.h[1] = (bf16)b;
  return t.u;
}

// ---------------- f32 -> bf16 convert (vectorized x4) ----------------
__global__ __launch_bounds__(256) void cvt_kernel(const float* __restrict__ in,
                                                  bf16* __restrict__ out, int n4) {
  int i = blockIdx.x * 256 + threadIdx.x;
  if (i >= n4) return;
  f32x4 f = *(const f32x4*)(in + (size_t)i * 4);
  bf16x4 b;
#pragma unroll
  for (int j = 0; j < 4; ++j) b[j] = (bf16)f[j];
  *(bf16x4*)(out + (size_t)i * 4) = b;
}

// ---------------- RoPE (in place on bf16 buffer) ----------------
__global__ __launch_bounds__(256) void rope_kernel(bf16* __restrict__ t,
                                                   const float* __restrict__ cosb,
                                                   const float* __restrict__ sinb,
                                                   int hlog, int stride, float scale) {
  int idx = blockIdx.x * 256 + threadIdx.x;
  int d   = idx & 31;
  int hh  = (idx >> 5) & ((1 << hlog) - 1);
  int row = idx >> (5 + hlog);
  int l   = row & 2047;
  float c1 = cosb[l * 64 + d],      s1 = sinb[l * 64 + d];
  float c2 = cosb[l * 64 + d + 32], s2 = sinb[l * 64 + d + 32];
  bf16* p = t + (size_t)row * stride + hh * 64 + d;
  float t1 = (float)p[0], t2 = (float)p[32];
  p[0]  = (bf16)((t1 * c1 - t2 * s1) * scale);
  p[32] = (bf16)((t2 * c2 + t1 * s2) * scale);
}

// ---------------- C = A * B^T  (A: MxK, B: NxK row-major, bf16 MFMA) -------
template <typename OutT>
__global__ __launch_bounds__(256) void gemm_bt(const bf16* __restrict__ A,
                                               const bf16* __restrict__ Bm,
                                               OutT* __restrict__ C,
                                               int M, int N, int K) {
  __shared__ bf16 a_lds[128 * 32];
  __shared__ bf16 b_lds[128 * 32];
  const int tid = threadIdx.x;
  const int w = tid >> 6, lane = tid & 63;
  const int lr = lane & 15, lg = lane >> 4;
  const int wr = w >> 1, wc = w & 1;
  const int m0 = blockIdx.y * 128, n0 = blockIdx.x * 128;

  f32x4 acc[4][4];
#pragma unroll
  for (int i = 0; i < 4; ++i)
#pragma unroll
    for (int j = 0; j < 4; ++j) acc[i][j] = f32x4{0.f, 0.f, 0.f, 0.f};

  for (int kt = 0; kt < K; kt += 32) {
#pragma unroll
    for (int i = 0; i < 2; ++i) {
      int c = tid + 256 * i;
      int row = c >> 2, kc = c & 3;
      GLDS16(A  + (size_t)(m0 + row) * K + kt + kc * 8, &a_lds[(w * 64 + 256 * i) * 8]);
      GLDS16(Bm + (size_t)(n0 + row) * K + kt + kc * 8, &b_lds[(w * 64 + 256 * i) * 8]);
    }
    __syncthreads();
    bf16x8 af[4], bfr[4];
#pragma unroll
    for (int t = 0; t < 4; ++t) {
      af[t]  = *(const bf16x8*)&a_lds[(wr * 64 + t * 16 + lr) * 32 + lg * 8];
      bfr[t] = *(const bf16x8*)&b_lds[(wc * 64 + t * 16 + lr) * 32 + lg * 8];
    }
#pragma unroll
    for (int mt = 0; mt < 4; ++mt)
#pragma unroll
      for (int nt = 0; nt < 4; ++nt)
        acc[mt][nt] = MFMA16(af[mt], bfr[nt], acc[mt][nt]);
    __syncthreads();
  }

#pragma unroll
  for (int mt = 0; mt < 4; ++mt)
#pragma unroll
    for (int nt = 0; nt < 4; ++nt)
#pragma unroll
      for (int r = 0; r < 4; ++r) {
        int mm = m0 + wr * 64 + mt * 16 + 4 * lg + r;
        int nn = n0 + wc * 64 + nt * 16 + lr;
        C[(size_t)mm * N + nn] = (OutT)acc[mt][nt][r];
      }
}

// ---------------- causal GQA flash attention (swapped QK^T, 32x32) ----------
// 512 blocks x 512 thr (8 waves); block owns 256 q rows (wave w: 32 rows).
// All blocks co-resident (LDS 34.8KB -> 4/CU cap, grid 2/CU => 16 waves/CU).
// Same-length pairing: id and id+256 share t so each CU keeps full density.
// Softmax in exp2 domain (log2e folded into q scale). V^T store kv-group
// XOR-swizzled by c8 (write 2-way=free, read b128 at floor). T5 setprio.
__global__ __launch_bounds__(512, 4) void attn_kernel(const bf16* __restrict__ q,
                                                      const bf16* __restrict__ k,
                                                      const bf16* __restrict__ v,
                                                      bf16* __restrict__ o) {
  constexpr int L = 2048;
  constexpr int QS = 3072;   // qkv row stride (elements)
  constexpr int OS = 2048;   // o row stride
  const int id = blockIdx.x;
  const int j5 = id & 255;
  const int t  = j5 >> 5;                       // 0..7 ; id & id+256 share t
  const int bh = (j5 & 31) | ((id >> 8) << 5);  // 0..63
  const int q0 = t * 256;
  const int b = bh >> 5, h = bh & 31, g = h >> 2;
  const int tid = threadIdx.x;
  const int w = tid >> 6, lane = tid & 63;
  const int lc = lane & 31;        // q column (QK) / d column (PV)
  const int H  = lane >> 5;
  const int off4 = 4 * H;
  const int qw = q0 + w * 32;
  const int qg = qw + lc;          // this lane's q row (global)

  __shared__ bf16     k_lds[2][64 * 64];   // [kv][d], 16B-chunk XOR-swizzled
  __shared__ unsigned vt_w[2][64 * 36];    // V^T [d][kv-pair], stride 36, kv-grp^c8

  // Q B-frag: col=q=lc, k(d) = 16s + 8H + j
  bf16x8 qf[4];
  {
    const bf16* qrow = q + (size_t)(b * L + qg) * QS + h * 64 + 8 * H;
#pragma unroll
    for (int s = 0; s < 4; ++s) qf[s] = *(const bf16x8*)(qrow + 16 * s);
  }

  f32x16 acc0, acc1;
#pragma unroll
  for (int r = 0; r < 16; ++r) { acc0[r] = 0.f; acc1[r] = 0.f; }
  float m_run = -1e30f, l_run = 0.f;

  uint4 uv;  // in-flight V (issue-early / write-late)

  auto stageK = [&](int kv0, int buf) {
    int kvr = tid >> 3, c8 = tid & 7;
    GLDS16(k + (size_t)(b * L + kv0 + kvr) * QS + g * 64 + ((c8 ^ (kvr & 7)) * 8),
           &k_lds[buf][tid * 8]);
  };
  auto loadV = [&](int kv0) {
    uv = *(const uint4*)(v + (size_t)(b * L + kv0 + (tid >> 3)) * QS + g * 64 + (tid & 7) * 8);
  };
  auto writeV = [&](int buf) {
    int kvr = tid >> 3, c8 = tid & 7;
    unsigned o0 = uv.x, o1 = uv.y, o2 = uv.z, o3 = uv.w;
    unsigned p0 = (unsigned)__shfl_xor((int)o0, 8);
    unsigned p1 = (unsigned)__shfl_xor((int)o1, 8);
    unsigned p2 = (unsigned)__shfl_xor((int)o2, 8);
    unsigned p3 = (unsigned)__shfl_xor((int)o3, 8);
    int pr = kvr & 1, kvw = kvr >> 1;
    int wbase = (kvw & 3) + 4 * ((kvw >> 2) ^ c8);   // kv-group XOR c8
#pragma unroll
    for (int jj = 0; jj < 4; ++jj) {
      unsigned ow = (jj >> 1) ? (pr ? o3 : o1) : (pr ? o2 : o0);
      unsigned pw = (jj >> 1) ? (pr ? p3 : p1) : (pr ? p2 : p0);
      unsigned oe = (jj & 1) ? (ow >> 16) : (ow & 0xFFFFu);
      unsigned pe = (jj & 1) ? (pw >> 16) : (pw & 0xFFFFu);
      unsigned lo = pr ? pe : oe;   // even kv
      unsigned hi = pr ? oe : pe;   // odd kv
      int d = 8 * c8 + 4 * pr + jj;
      vt_w[buf][d * 36 + wbase] = lo | (hi << 16);
    }
  };

  const int nt = 4 * t + 4;   // kv tiles 0 .. q0+192
  stageK(0, 0);
  loadV(0);
  writeV(0);
  __syncthreads();

  for (int it = 0; it < nt; ++it) {
    const int cur = it & 1;
    const int kv0 = it * 64;
    const bool notlast = (it + 1 < nt);
    if (notlast) {
      stageK(kv0 + 64, cur ^ 1);
      loadV(kv0 + 64);
    }

    if (kv0 <= qw + 31) {   // wave-uniform skip of fully-masked tiles
      // ---- S = K Q (A=K rows=kv, B=Q cols=q), exp2 domain ----
      f32x16 p0, p1;
#pragma unroll
      for (int r = 0; r < 16; ++r) { p0[r] = 0.f; p1[r] = 0.f; }
      __builtin_amdgcn_s_setprio(1);
#pragma unroll
      for (int s = 0; s < 4; ++s) {
        int ch = ((2 * s + H) ^ (lc & 7)) * 8;
        bf16x8 kf0 = *(const bf16x8*)&k_lds[cur][lc * 64 + ch];
        bf16x8 kf1 = *(const bf16x8*)&k_lds[cur][(32 + lc) * 64 + ch];
        p0 = MFMA32(kf0, qf[s], p0);
        p1 = MFMA32(kf1, qf[s], p1);
      }
      __builtin_amdgcn_s_setprio(0);

      // ---- causal mask: D row=kv=(r&3)+8(r>>2)+4H, col=q=lc ----
      if (kv0 + 63 > qw) {
#pragma unroll
        for (int r = 0; r < 16; ++r) {
          int kvl = kv0 + (r & 3) + 8 * (r >> 2) + off4;
          if (kvl > qg)      p0[r] = -1e30f;
          if (kvl + 32 > qg) p1[r] = -1e30f;
        }
      }

      // ---- online softmax, in-register (T12) + defer-max (T13) ----
      float mt = -1e30f;
#pragma unroll
      for (int r = 0; r < 16; ++r) mt = fmaxf(mt, fmaxf(p0[r], p1[r]));
      mt = fmaxf(mt, __shfl_xor(mt, 32));
      const int defer = __all(mt <= m_run + 11.0f);   // ~8 nats in log2 domain
      float alpha = 1.f;
      if (!defer) {
        float mn = fmaxf(m_run, mt);
        alpha = exp2f(m_run - mn);
        m_run = mn;
      }
      float ls = 0.f;
#pragma unroll
      for (int r = 0; r < 16; ++r) {
        p0[r] = exp2f(p0[r] - m_run);
        p1[r] = exp2f(p1[r] - m_run);
        ls += p0[r] + p1[r];
      }
      ls += __shfl_xor(ls, 32);
      l_run = l_run * alpha + ls;
      if (!defer) {
#pragma unroll
        for (int r = 0; r < 16; ++r) {
          float aq = __shfl(alpha, ((r & 3) + 8 * (r >> 2)) + off4);
          acc0[r] *= aq;
          acc1[r] *= aq;
        }
      }

      // ---- P -> bf16 A-frags: pack pairs, permlane32_swap redistributes ----
      unsigned A[16];
#pragma unroll
      for (int i = 0; i < 8; ++i) {
        A[i]     = pk2(p0[2 * i], p0[2 * i + 1]);
        A[8 + i] = pk2(p1[2 * i], p1[2 * i + 1]);
      }
#pragma unroll
      for (int base = 0; base < 16; base += 4) {
        PLSWAP(A[base],     A[base + 2]);
        PLSWAP(A[base + 1], A[base + 3]);
      }

      // ---- O += P V  (A=P rows=q, B=V cols=d) ----
      __builtin_amdgcn_s_setprio(1);
#pragma unroll
      for (int sp = 0; sp < 4; ++sp) {
        union { unsigned u[4]; bf16x8 v8; } pa;
#pragma unroll
        for (int jx = 0; jx < 4; ++jx) pa.u[jx] = A[4 * sp + jx];
        int g0 = (2 * sp + H) ^ (lc >> 3);
        int g1 = (2 * sp + H) ^ (4 + (lc >> 3));
        bf16x8 vf0 = *(const bf16x8*)&vt_w[cur][lc * 36 + 4 * g0];
        bf16x8 vf1 = *(const bf16x8*)&vt_w[cur][(32 + lc) * 36 + 4 * g1];
        acc0 = MFMA32(pa.v8, vf0, acc0);
        acc1 = MFMA32(pa.v8, vf1, acc1);
      }
      __builtin_amdgcn_s_setprio(0);
    }

    if (notlast) writeV(cur ^ 1);
    __syncthreads();
  }

  // ---- epilogue: divide by l (per-q, via shfl) and store ----
#pragma unroll
  for (int r = 0; r < 16; ++r) {
    int qrow = (r & 3) + 8 * (r >> 2) + off4;
    float lq = __shfl(l_run, qrow);
    float inv = 1.f / lq;
    size_t orow = (size_t)(b * L + qw + qrow) * OS + h * 64;
    o[orow + lc]      = (bf16)(acc0[r] * inv);
    o[orow + 32 + lc] = (bf16)(acc1[r] * inv);
  }
}

extern "C" void kernel_launch(void* const* d_in, const int* in_sizes, int n_in,
                              void* d_out, int out_size, void* d_ws, size_t ws_size,
                              hipStream_t stream) {
  (void)in_sizes; (void)n_in; (void)out_size; (void)ws_size;
  const float* x    = (const float*)d_in[0];
  const float* cosb = (const float*)d_in[1];
  const float* sinb = (const float*)d_in[2];
  const float* Wq   = (const float*)d_in[3];
  const float* Wk   = (const float*)d_in[4];
  const float* Wv   = (const float*)d_in[5];
  const float* Wo   = (const float*)d_in[6];

  constexpr int B = 2, L = 2048, D = 2048, H = 32, G = 8;
  constexpr int M = B * L;           // 4096
  constexpr int DKV = G * 64;        // 512
  constexpr int NQKV = D + 2 * DKV;  // 3072

  char* p = (char*)d_ws;
  bf16* xb   = (bf16*)p; p += (size_t)M * D * 2;
  bf16* wqkv = (bf16*)p; p += (size_t)NQKV * D * 2;
  bf16* wob  = (bf16*)p; p += (size_t)D * D * 2;
  bf16* qkv  = (bf16*)p; p += (size_t)M * NQKV * 2;
  bf16* ob   = xb;  // xb dead after QKV GEMM

  auto cvt = [&](const float* src, bf16* dst, size_t n) {
    int n4 = (int)(n / 4);
    cvt_kernel<<<(n4 + 255) / 256, 256, 0, stream>>>(src, dst, n4);
  };
  cvt(x,  xb,                           (size_t)M * D);
  cvt(Wq, wqkv,                         (size_t)D * D);
  cvt(Wk, wqkv + (size_t)D * D,         (size_t)DKV * D);
  cvt(Wv, wqkv + (size_t)(D + DKV) * D, (size_t)DKV * D);
  cvt(Wo, wob,                          (size_t)D * D);

  gemm_bt<bf16><<<dim3(NQKV / 128, M / 128), 256, 0, stream>>>(xb, wqkv, qkv, M, NQKV, D);

  // RoPE in place; fold softmax scale (1/8) * log2(e) into q (exp2-domain softmax)
  rope_kernel<<<(M * H * 32) / 256, 256, 0, stream>>>(qkv, cosb, sinb, 5, NQKV,
                                                      0.18033688011112042f);
  rope_kernel<<<(M * G * 32) / 256, 256, 0, stream>>>(qkv + D, cosb, sinb, 3, NQKV, 1.0f);

  attn_kernel<<<dim3(512), 512, 0, stream>>>(qkv, qkv + D, qkv + D + DKV, ob);

  gemm_bt<float><<<dim3(D / 128, M / 128), 256, 0, stream>>>(ob, wob, (float*)d_out, M, D, D);
}

// Round 8
// 273.792 us; speedup vs baseline: 1.1290x; 1.1290x over previous
//
#include <hip/hip_runtime.h>

typedef __bf16 bf16;
typedef __bf16 bf16x4 __attribute__((ext_vector_type(4)));
typedef __bf16 bf16x8 __attribute__((ext_vector_type(8)));
typedef float  f32x4  __attribute__((ext_vector_type(4)));
typedef float  f32x16 __attribute__((ext_vector_type(16)));

#define GLDS16(gsrc, ldst)                                                    \
  __builtin_amdgcn_global_load_lds(                                          \
      (const __attribute__((address_space(1))) void*)(gsrc),                 \
      (__attribute__((address_space(3))) void*)(ldst), 16, 0, 0)

#define MFMA16(a, b, c) __builtin_amdgcn_mfma_f32_16x16x32_bf16((a), (b), (c), 0, 0, 0)
#define MFMA32(a, b, c) __builtin_amdgcn_mfma_f32_32x32x16_bf16((a), (b), (c), 0, 0, 0)
// exchange a's hi-32-lane half with b's lo-32-lane half (gfx950)
#define PLSWAP(a, b) asm volatile("v_permlane32_swap_b32 %0, %1" : "+v"(a), "+v"(b))

__device__ inline unsigned pk2(float a, float b) {
  union { bf16 h[2]; unsigned u; } t;
  t.h[0] = (bf16)a; t.h[1] = (bf16)b;
  return t.u;
}

// ---------------- f32 -> bf16 convert (vectorized x4) ----------------
__global__ __launch_bounds__(256) void cvt_kernel(const float* __restrict__ in,
                                                  bf16* __restrict__ out, int n4) {
  int i = blockIdx.x * 256 + threadIdx.x;
  if (i >= n4) return;
  f32x4 f = *(const f32x4*)(in + (size_t)i * 4);
  bf16x4 b;
#pragma unroll
  for (int j = 0; j < 4; ++j) b[j] = (bf16)f[j];
  *(bf16x4*)(out + (size_t)i * 4) = b;
}

// ---------------- RoPE (in place on bf16 buffer) ----------------
__global__ __launch_bounds__(256) void rope_kernel(bf16* __restrict__ t,
                                                   const float* __restrict__ cosb,
                                                   const float* __restrict__ sinb,
                                                   int hlog, int stride, float scale) {
  int idx = blockIdx.x * 256 + threadIdx.x;
  int d   = idx & 31;
  int hh  = (idx >> 5) & ((1 << hlog) - 1);
  int row = idx >> (5 + hlog);
  int l   = row & 2047;
  float c1 = cosb[l * 64 + d],      s1 = sinb[l * 64 + d];
  float c2 = cosb[l * 64 + d + 32], s2 = sinb[l * 64 + d + 32];
  bf16* p = t + (size_t)row * stride + hh * 64 + d;
  float t1 = (float)p[0], t2 = (float)p[32];
  p[0]  = (bf16)((t1 * c1 - t2 * s1) * scale);
  p[32] = (bf16)((t2 * c2 + t1 * s2) * scale);
}

// ---------------- C = A * B^T  (A: MxK, B: NxK row-major, bf16 MFMA) -------
template <typename OutT>
__global__ __launch_bounds__(256) void gemm_bt(const bf16* __restrict__ A,
                                               const bf16* __restrict__ Bm,
                                               OutT* __restrict__ C,
                                               int M, int N, int K) {
  __shared__ bf16 a_lds[128 * 32];
  __shared__ bf16 b_lds[128 * 32];
  const int tid = threadIdx.x;
  const int w = tid >> 6, lane = tid & 63;
  const int lr = lane & 15, lg = lane >> 4;
  const int wr = w >> 1, wc = w & 1;
  const int m0 = blockIdx.y * 128, n0 = blockIdx.x * 128;

  f32x4 acc[4][4];
#pragma unroll
  for (int i = 0; i < 4; ++i)
#pragma unroll
    for (int j = 0; j < 4; ++j) acc[i][j] = f32x4{0.f, 0.f, 0.f, 0.f};

  for (int kt = 0; kt < K; kt += 32) {
#pragma unroll
    for (int i = 0; i < 2; ++i) {
      int c = tid + 256 * i;
      int row = c >> 2, kc = c & 3;
      GLDS16(A  + (size_t)(m0 + row) * K + kt + kc * 8, &a_lds[(w * 64 + 256 * i) * 8]);
      GLDS16(Bm + (size_t)(n0 + row) * K + kt + kc * 8, &b_lds[(w * 64 + 256 * i) * 8]);
    }
    __syncthreads();
    bf16x8 af[4], bfr[4];
#pragma unroll
    for (int t = 0; t < 4; ++t) {
      af[t]  = *(const bf16x8*)&a_lds[(wr * 64 + t * 16 + lr) * 32 + lg * 8];
      bfr[t] = *(const bf16x8*)&b_lds[(wc * 64 + t * 16 + lr) * 32 + lg * 8];
    }
#pragma unroll
    for (int mt = 0; mt < 4; ++mt)
#pragma unroll
      for (int nt = 0; nt < 4; ++nt)
        acc[mt][nt] = MFMA16(af[mt], bfr[nt], acc[mt][nt]);
    __syncthreads();
  }

#pragma unroll
  for (int mt = 0; mt < 4; ++mt)
#pragma unroll
    for (int nt = 0; nt < 4; ++nt)
#pragma unroll
      for (int r = 0; r < 4; ++r) {
        int mm = m0 + wr * 64 + mt * 16 + 4 * lg + r;
        int nn = n0 + wc * 64 + nt * 16 + lr;
        C[(size_t)mm * N + nn] = (OutT)acc[mt][nt][r];
      }
}

// ---------------- causal GQA flash attention (swapped QK^T, 32x32) ----------
// 1024 blocks x 256 thr (4 waves); block owns 128 q rows (wave w: 32 rows).
// Latin-square q-tile assignment: CU c hosts {c,c+256,c+512,c+768} (round-robin
// placement) -> same bh, u-set summing to 30 -> EVERY CU runs exactly 68
// kv-tile iterations. 4 blocks/CU (LDS 34.8KB) = 16 waves/CU sustained, and
// barriers couple only 4 waves. Softmax in exp2 domain, in-register (swapped
// mfma(K,Q)); defer-max THR; V^T kv-group XOR-swizzled; K chunk-XOR swizzled.
__global__ __launch_bounds__(256, 4) void attn_kernel(const bf16* __restrict__ q,
                                                      const bf16* __restrict__ k,
                                                      const bf16* __restrict__ v,
                                                      bf16* __restrict__ o) {
  constexpr int L = 2048;
  constexpr int QS = 3072;   // qkv row stride (elements)
  constexpr int OS = 2048;   // o row stride
  const int id = blockIdx.x;
  const int bh = id & 63;
  const int pq = (id >> 6) & 3;
  const int gq = id >> 8;
  // nibble table rows {15,0,14,1},{13,2,12,3},{11,4,10,5},{9,6,8,7}
  const int u  = (int)((0x78695A4B3C2D1E0FULL >> (4 * ((pq << 2) | gq))) & 15);
  const int q0 = u * 128;
  const int b = bh >> 5, h = bh & 31, g = h >> 2;
  const int tid = threadIdx.x;
  const int w = tid >> 6, lane = tid & 63;
  const int lc = lane & 31;        // q column (QK) / d column (PV)
  const int H  = lane >> 5;
  const int off4 = 4 * H;
  const int qw = q0 + w * 32;
  const int qg = qw + lc;          // this lane's q row (global)

  __shared__ bf16     k_lds[2][64 * 64];   // [kv][d], 16B-chunk XOR-swizzled
  __shared__ unsigned vt_w[2][64 * 36];    // V^T [d][kv-pair], stride 36, kv-grp^c8

  // Q B-frag: col=q=lc, k(d) = 16s + 8H + j
  bf16x8 qf[4];
  {
    const bf16* qrow = q + (size_t)(b * L + qg) * QS + h * 64 + 8 * H;
#pragma unroll
    for (int s = 0; s < 4; ++s) qf[s] = *(const bf16x8*)(qrow + 16 * s);
  }

  f32x16 acc0, acc1;
#pragma unroll
  for (int r = 0; r < 16; ++r) { acc0[r] = 0.f; acc1[r] = 0.f; }
  float m_run = -1e30f, l_run = 0.f;

  uint4 uv[2];  // in-flight V (issue-early / write-late)

  auto stageK = [&](int kv0, int buf) {
#pragma unroll
    for (int i = 0; i < 2; ++i) {
      int c = tid + 256 * i;
      int kvr = c >> 3, c8 = c & 7;
      GLDS16(k + (size_t)(b * L + kv0 + kvr) * QS + g * 64 + ((c8 ^ (kvr & 7)) * 8),
             &k_lds[buf][(w * 64 + 256 * i) * 8]);
    }
  };
  auto loadV = [&](int kv0) {
#pragma unroll
    for (int i = 0; i < 2; ++i) {
      int c = tid + 256 * i;
      uv[i] = *(const uint4*)(v + (size_t)(b * L + kv0 + (c >> 3)) * QS + g * 64 + (c & 7) * 8);
    }
  };
  auto writeV = [&](int buf) {
#pragma unroll
    for (int i = 0; i < 2; ++i) {
      int c = tid + 256 * i;
      int kvr = c >> 3, c8 = c & 7;
      unsigned o0 = uv[i].x, o1 = uv[i].y, o2 = uv[i].z, o3 = uv[i].w;
      unsigned p0 = (unsigned)__shfl_xor((int)o0, 8);
      unsigned p1 = (unsigned)__shfl_xor((int)o1, 8);
      unsigned p2 = (unsigned)__shfl_xor((int)o2, 8);
      unsigned p3 = (unsigned)__shfl_xor((int)o3, 8);
      int pr = kvr & 1, kvw = kvr >> 1;
      int wbase = (kvw & 3) + 4 * ((kvw >> 2) ^ c8);   // kv-group XOR c8
#pragma unroll
      for (int jj = 0; jj < 4; ++jj) {
        unsigned ow = (jj >> 1) ? (pr ? o3 : o1) : (pr ? o2 : o0);
        unsigned pw = (jj >> 1) ? (pr ? p3 : p1) : (pr ? p2 : p0);
        unsigned oe = (jj & 1) ? (ow >> 16) : (ow & 0xFFFFu);
        unsigned pe = (jj & 1) ? (pw >> 16) : (pw & 0xFFFFu);
        unsigned lo = pr ? pe : oe;   // even kv
        unsigned hi = pr ? oe : pe;   // odd kv
        int d = 8 * c8 + 4 * pr + jj;
        vt_w[buf][d * 36 + wbase] = lo | (hi << 16);
      }
    }
  };

  const int nt = 2 * u + 2;   // kv tiles 0 .. q0+64
  stageK(0, 0);
  loadV(0);
  writeV(0);
  __syncthreads();

  for (int it = 0; it < nt; ++it) {
    const int cur = it & 1;
    const int kv0 = it * 64;
    const bool notlast = (it + 1 < nt);
    if (notlast) {
      stageK(kv0 + 64, cur ^ 1);
      loadV(kv0 + 64);
    }

    if (kv0 <= qw + 31) {   // wave-uniform skip of fully-masked tiles
      // ---- S = K Q (A=K rows=kv, B=Q cols=q), exp2 domain ----
      f32x16 p0, p1;
#pragma unroll
      for (int r = 0; r < 16; ++r) { p0[r] = 0.f; p1[r] = 0.f; }
      __builtin_amdgcn_s_setprio(1);
#pragma unroll
      for (int s = 0; s < 4; ++s) {
        int ch = ((2 * s + H) ^ (lc & 7)) * 8;
        bf16x8 kf0 = *(const bf16x8*)&k_lds[cur][lc * 64 + ch];
        bf16x8 kf1 = *(const bf16x8*)&k_lds[cur][(32 + lc) * 64 + ch];
        p0 = MFMA32(kf0, qf[s], p0);
        p1 = MFMA32(kf1, qf[s], p1);
      }
      __builtin_amdgcn_s_setprio(0);

      // ---- causal mask: D row=kv=(r&3)+8(r>>2)+4H, col=q=lc ----
      if (kv0 + 63 > qw) {
#pragma unroll
        for (int r = 0; r < 16; ++r) {
          int kvl = kv0 + (r & 3) + 8 * (r >> 2) + off4;
          if (kvl > qg)      p0[r] = -1e30f;
          if (kvl + 32 > qg) p1[r] = -1e30f;
        }
      }

      // ---- online softmax, in-register (T12) + defer-max (T13) ----
      float mt = -1e30f;
#pragma unroll
      for (int r = 0; r < 16; ++r) mt = fmaxf(mt, fmaxf(p0[r], p1[r]));
      mt = fmaxf(mt, __shfl_xor(mt, 32));
      const int defer = __all(mt <= m_run + 11.0f);   // ~8 nats in log2 domain
      float alpha = 1.f;
      if (!defer) {
        float mn = fmaxf(m_run, mt);
        alpha = exp2f(m_run - mn);
        m_run = mn;
      }
      float ls = 0.f;
#pragma unroll
      for (int r = 0; r < 16; ++r) {
        p0[r] = exp2f(p0[r] - m_run);
        p1[r] = exp2f(p1[r] - m_run);
        ls += p0[r] + p1[r];
      }
      ls += __shfl_xor(ls, 32);
      l_run = l_run * alpha + ls;
      if (!defer) {
#pragma unroll
        for (int r = 0; r < 16; ++r) {
          float aq = __shfl(alpha, ((r & 3) + 8 * (r >> 2)) + off4);
          acc0[r] *= aq;
          acc1[r] *= aq;
        }
      }

      // ---- P -> bf16 A-frags: pack pairs, permlane32_swap redistributes ----
      unsigned A[16];
#pragma unroll
      for (int i = 0; i < 8; ++i) {
        A[i]     = pk2(p0[2 * i], p0[2 * i + 1]);
        A[8 + i] = pk2(p1[2 * i], p1[2 * i + 1]);
      }
#pragma unroll
      for (int base = 0; base < 16; base += 4) {
        PLSWAP(A[base],     A[base + 2]);
        PLSWAP(A[base + 1], A[base + 3]);
      }

      // ---- O += P V  (A=P rows=q, B=V cols=d) ----
      __builtin_amdgcn_s_setprio(1);
#pragma unroll
      for (int sp = 0; sp < 4; ++sp) {
        union { unsigned u[4]; bf16x8 v8; } pa;
#pragma unroll
        for (int jx = 0; jx < 4; ++jx) pa.u[jx] = A[4 * sp + jx];
        int g0 = (2 * sp + H) ^ (lc >> 3);
        int g1 = (2 * sp + H) ^ (4 + (lc >> 3));
        bf16x8 vf0 = *(const bf16x8*)&vt_w[cur][lc * 36 + 4 * g0];
        bf16x8 vf1 = *(const bf16x8*)&vt_w[cur][(32 + lc) * 36 + 4 * g1];
        acc0 = MFMA32(pa.v8, vf0, acc0);
        acc1 = MFMA32(pa.v8, vf1, acc1);
      }
      __builtin_amdgcn_s_setprio(0);
    }

    if (notlast) writeV(cur ^ 1);
    __syncthreads();
  }

  // ---- epilogue: divide by l (per-q, via shfl) and store ----
#pragma unroll
  for (int r = 0; r < 16; ++r) {
    int qrow = (r & 3) + 8 * (r >> 2) + off4;
    float lq = __shfl(l_run, qrow);
    float inv = 1.f / lq;
    size_t orow = (size_t)(b * L + qw + qrow) * OS + h * 64;
    o[orow + lc]      = (bf16)(acc0[r] * inv);
    o[orow + 32 + lc] = (bf16)(acc1[r] * inv);
  }
}

extern "C" void kernel_launch(void* const* d_in, const int* in_sizes, int n_in,
                              void* d_out, int out_size, void* d_ws, size_t ws_size,
                              hipStream_t stream) {
  (void)in_sizes; (void)n_in; (void)out_size; (void)ws_size;
  const float* x    = (const float*)d_in[0];
  const float* cosb = (const float*)d_in[1];
  const float* sinb = (const float*)d_in[2];
  const float* Wq   = (const float*)d_in[3];
  const float* Wk   = (const float*)d_in[4];
  const float* Wv   = (const float*)d_in[5];
  const float* Wo   = (const float*)d_in[6];

  constexpr int B = 2, L = 2048, D = 2048, H = 32, G = 8;
  constexpr int M = B * L;           // 4096
  constexpr int DKV = G * 64;        // 512
  constexpr int NQKV = D + 2 * DKV;  // 3072

  char* p = (char*)d_ws;
  bf16* xb   = (bf16*)p; p += (size_t)M * D * 2;
  bf16* wqkv = (bf16*)p; p += (size_t)NQKV * D * 2;
  bf16* wob  = (bf16*)p; p += (size_t)D * D * 2;
  bf16* qkv  = (bf16*)p; p += (size_t)M * NQKV * 2;
  bf16* ob   = xb;  // xb dead after QKV GEMM

  auto cvt = [&](const float* src, bf16* dst, size_t n) {
    int n4 = (int)(n / 4);
    cvt_kernel<<<(n4 + 255) / 256, 256, 0, stream>>>(src, dst, n4);
  };
  cvt(x,  xb,                           (size_t)M * D);
  cvt(Wq, wqkv,                         (size_t)D * D);
  cvt(Wk, wqkv + (size_t)D * D,         (size_t)DKV * D);
  cvt(Wv, wqkv + (size_t)(D + DKV) * D, (size_t)DKV * D);
  cvt(Wo, wob,                          (size_t)D * D);

  gemm_bt<bf16><<<dim3(NQKV / 128, M / 128), 256, 0, stream>>>(xb, wqkv, qkv, M, NQKV, D);

  // RoPE in place; fold softmax scale (1/8) * log2(e) into q (exp2-domain softmax)
  rope_kernel<<<(M * H * 32) / 256, 256, 0, stream>>>(qkv, cosb, sinb, 5, NQKV,
                                                      0.18033688011112042f);
  rope_kernel<<<(M * G * 32) / 256, 256, 0, stream>>>(qkv + D, cosb, sinb, 3, NQKV, 1.0f);

  attn_kernel<<<dim3(1024), 256, 0, stream>>>(qkv, qkv + D, qkv + D + DKV, ob);

  gemm_bt<float><<<dim3(D / 128, M / 128), 256, 0, stream>>>(ob, wob, (float*)d_out, M, D, D);
}